// Round 10
// baseline (862.602 us; speedup 1.0000x reference)
//
#include <hip/hip_runtime.h>
#include <hip/hip_cooperative_groups.h>
#include <stdint.h>

namespace cg = cooperative_groups;

typedef _Float16 half8 __attribute__((ext_vector_type(8)));
typedef float float4v __attribute__((ext_vector_type(4)));

__host__ __device__ inline void tf2x32(uint32_t k0, uint32_t k1,
                                       uint32_t x0, uint32_t x1,
                                       uint32_t* o0, uint32_t* o1) {
  const uint32_t ks2 = k0 ^ k1 ^ 0x1BD11BDAu;
#define ROTL(v, s) (((v) << (s)) | ((v) >> (32 - (s))))
#define RND(r) do { x0 += x1; x1 = ROTL(x1, r); x1 ^= x0; } while (0)
  x0 += k0; x1 += k1;
  RND(13); RND(15); RND(26); RND(6);
  x0 += k1; x1 += ks2 + 1u;
  RND(17); RND(29); RND(16); RND(24);
  x0 += ks2; x1 += k0 + 2u;
  RND(13); RND(15); RND(26); RND(6);
  x0 += k0; x1 += k1 + 3u;
  RND(17); RND(29); RND(16); RND(24);
  x0 += k1; x1 += ks2 + 4u;
  RND(13); RND(15); RND(26); RND(6);
  x0 += ks2; x1 += k0 + 5u;
  *o0 = x0; *o1 = x1;
#undef RND
#undef ROTL
}

__device__ inline bool drop_keep(uint32_t k0, uint32_t k1, uint32_t idx) {
  uint32_t o0, o1;
  tf2x32(k0, k1, 0u, idx, &o0, &o1);
  uint32_t bits = o0 ^ o1;
  float u = __uint_as_float((bits >> 9) | 0x3f800000u) - 1.0f;
  return u < 0.4f;
}

struct MegaParams {
  const float* x;
  const int* row;
  const int* col;
  const float* W0; const float* b0;
  const float* W1; const float* b1;
  const float* W2; const float* b2;
  float* out;
  int* cnt;
  float* dis;
  uint16_t* cs;
  _Float16* ya; _Float16* ysa; _Float16* yb; _Float16* ysb; _Float16* wh;
  uint32_t dk[6];        // threefry keys for dropout layers 0..2
  int n, e, rpx, nchunk8, nbdrop, nbconv;
};

// One conv layer (grid-strided over 16-row tiles). Body identical to R9 k_conv.
template<int COUT, bool RELU, bool DROPN, bool WBF>
__device__ void conv_phase(_Float16 (*xp)[136], const MegaParams& p,
                           const _Float16* yg_, const _Float16* ysg_,
                           const _Float16* wt_, const float* b_,
                           float* outf, _Float16* outb, _Float16* outs,
                           uint32_t nk0, uint32_t nk1) {
  const _Float16* __restrict__ yg  = yg_;
  const _Float16* __restrict__ ysg = ysg_;
  const _Float16* __restrict__ wt  = wt_;
  const uint16_t* __restrict__ cs  = p.cs;
  const int*      __restrict__ cnt = p.cnt;
  const float*    __restrict__ dis = p.dis;
  const int n    = p.n;
  const int wave = threadIdx.x >> 6;
  const int t    = threadIdx.x & 63;

  for (int vb = blockIdx.x; vb < p.nbconv; vb += gridDim.x) {
    const int row0 = vb * 16;
    // ---- Phase 1: gather (16-deep batches + 8-tail, pads hit zero row) ----
    for (int i = 0; i < 4; ++i) {
      const int rl = wave * 4 + i;
      const int r  = row0 + rl;
      if (r < n) {
        float acc = 0.0f;
        const int d    = cnt[r];
        const int cn   = d < 64 ? d : 64;
        const int rnd  = (cn + 7) & ~7;
        const int base = r << 6;
        int j = 0;
        for (; j + 16 <= rnd; j += 16) {
          const uint4 c0 = *(const uint4*)&cs[base + j];
          const uint4 c1 = *(const uint4*)&cs[base + j + 8];
          uint32_t c[16];
          c[0]  = c0.x & 0xffffu; c[1]  = c0.x >> 16;
          c[2]  = c0.y & 0xffffu; c[3]  = c0.y >> 16;
          c[4]  = c0.z & 0xffffu; c[5]  = c0.z >> 16;
          c[6]  = c0.w & 0xffffu; c[7]  = c0.w >> 16;
          c[8]  = c1.x & 0xffffu; c[9]  = c1.x >> 16;
          c[10] = c1.y & 0xffffu; c[11] = c1.y >> 16;
          c[12] = c1.z & 0xffffu; c[13] = c1.z >> 16;
          c[14] = c1.w & 0xffffu; c[15] = c1.w >> 16;
          _Float16 xv[16];
          #pragma unroll
          for (int k = 0; k < 16; ++k) xv[k] = ysg[(c[k] << 6) + t];
          #pragma unroll
          for (int k = 0; k < 16; ++k) acc += (float)xv[k];
        }
        if (j < rnd) {
          const uint4 cc = *(const uint4*)&cs[base + j];
          uint32_t c[8];
          c[0] = cc.x & 0xffffu; c[1] = cc.x >> 16;
          c[2] = cc.y & 0xffffu; c[3] = cc.y >> 16;
          c[4] = cc.z & 0xffffu; c[5] = cc.z >> 16;
          c[6] = cc.w & 0xffffu; c[7] = cc.w >> 16;
          _Float16 xv[8];
          #pragma unroll
          for (int k = 0; k < 8; ++k) xv[k] = ysg[(c[k] << 6) + t];
          #pragma unroll
          for (int k = 0; k < 8; ++k) acc += (float)xv[k];
        }
        xp[rl][t]      = yg[(uint32_t)(r << 6) + t];
        xp[rl][64 + t] = (_Float16)(-dis[r] * acc);
      }
    }
    __syncthreads();

    // ---- Phase 2: MFMA (B fragments from global f16 W^T) ----
    constexpr int NW = COUT / 16;
    const int nn   = t & 15;
    const int quad = t >> 4;
    if (wave < NW) {
      const int colg = wave * 16 + nn;
      float4v acc = {0.f, 0.f, 0.f, 0.f};
      #pragma unroll
      for (int ks = 0; ks < 4; ++ks) {
        half8 a  = *(const half8*)&xp[nn][quad * 8 + 32 * ks];
        half8 bb = *(const half8*)&wt[(size_t)colg * 128 + quad * 8 + 32 * ks];
        acc = __builtin_amdgcn_mfma_f32_16x16x32_f16(a, bb, acc, 0, 0, 0);
      }
      // ---- Phase 3: epilogue ----
      const float bias = b_[colg];
      #pragma unroll
      for (int rg = 0; rg < 4; ++rg) {
        const int rl = quad * 4 + rg;
        const int rr = row0 + rl;
        if (rr < n) {
          float v = acc[rg] + bias;
          if (RELU) v = fmaxf(v, 0.0f);
          if (DROPN) {
            if (drop_keep(nk0, nk1, (uint32_t)(rr * 64 + colg))) v *= 2.5f;
            else v = 0.0f;
          }
          if (WBF) {
            outb[(size_t)rr * COUT + colg] = (_Float16)v;
            outs[(size_t)rr * COUT + colg] = (_Float16)(dis[rr] * v);
          } else {
            outf[(size_t)rr * COUT + colg] = v;
          }
        }
      }
    }
    __syncthreads();   // xp reused by next grid-stride tile
  }
}

// Persistent cooperative mega-kernel: the whole ChebNet forward in one launch.
__global__ __launch_bounds__(256, 8) void k_mega(MegaParams p) {
  __shared__ __align__(16) _Float16 xp[16][136];
  cg::grid_group grid = cg::this_grid();
  const int gtid = blockIdx.x * 256 + threadIdx.x;
  const int gsz  = gridDim.x * 256;

  // ---- phase 0: zero cnt, convert W -> f16 W^T, zero dummy gather rows ----
  for (int i = gtid; i < p.n; i += gsz) p.cnt[i] = 0;
  for (int d = gtid; d < 20480; d += gsz) {
    if (d < 8192) {
      int o = d >> 7, k = d & 127;
      p.wh[d] = (_Float16)p.W0[k * 64 + o];
    } else if (d < 16384) {
      int d1 = d - 8192, o = d1 >> 7, k = d1 & 127;
      p.wh[d] = (_Float16)p.W1[k * 64 + o];
    } else {
      int d2 = d - 16384, o = d2 >> 7, k = d2 & 127;
      p.wh[d] = (_Float16)p.W2[k * 32 + o];
    }
  }
  if (gtid < 64) {
    p.ysa[((size_t)p.n << 6) + gtid] = (_Float16)0.f;
    p.ysb[((size_t)p.n << 6) + gtid] = (_Float16)0.f;
  }
  grid.sync();

  // ---- phase 1: XCD-owned slotted-CSR fill (owner = vb&7; gridDim%8==0) ----
  for (int vb = blockIdx.x; vb < p.nchunk8; vb += gridDim.x) {
    const int owner = vb & 7;
    const int i = (vb >> 3) * 256 + threadIdx.x;
    if (i < p.e) {
      int r = p.row[i];
      if (r / p.rpx == owner) {
        int pos = atomicAdd(&p.cnt[r], 1);
        if (pos < 64) p.cs[(r << 6) + pos] = (uint16_t)p.col[i];
      }
    }
  }
  grid.sync();

  // ---- phase 2: layer-0 dropout + dis + slot padding ----
  for (int vb = blockIdx.x; vb < p.nbdrop; vb += gridDim.x) {
    const int i = vb * 256 + threadIdx.x;      // nbdrop*256 == n*64 exactly
    const int r = i >> 6;
    const int t = i & 63;
    const int d = p.cnt[r];
    const float dis_r = (d > 0) ? rsqrtf((float)d) : 0.0f;
    float v = drop_keep(p.dk[0], p.dk[1], (uint32_t)i) ? p.x[i] * 2.5f : 0.0f;
    p.ya[i]  = (_Float16)v;
    p.ysa[i] = (_Float16)(dis_r * v);
    if (t == 0) p.dis[r] = dis_r;
    const int cn  = d < 64 ? d : 64;
    const int rnd = (cn + 7) & ~7;
    if (t >= cn && t < rnd) p.cs[(r << 6) + t] = (uint16_t)p.n;
  }
  grid.sync();

  // ---- phases 3-5: the three ChebConv layers ----
  conv_phase<64, true,  true,  true >(xp, p, p.ya, p.ysa, p.wh,         p.b0,
                                      nullptr, p.yb, p.ysb, p.dk[2], p.dk[3]);
  grid.sync();
  conv_phase<64, true,  true,  true >(xp, p, p.yb, p.ysb, p.wh + 8192,  p.b1,
                                      nullptr, p.ya, p.ysa, p.dk[4], p.dk[5]);
  grid.sync();
  conv_phase<32, false, false, false>(xp, p, p.ya, p.ysa, p.wh + 16384, p.b2,
                                      p.out, nullptr, nullptr, 0u, 0u);
}

extern "C" void kernel_launch(void* const* d_in, const int* in_sizes, int n_in,
                              void* d_out, int out_size, void* d_ws, size_t ws_size,
                              hipStream_t stream) {
  const int n = in_sizes[0] / 64;   // 50000
  const int e = in_sizes[1] / 2;    // 800000

  size_t off = 0;
  auto carve = [&](size_t elems) {   // elems in int32 units, 1KB-aligned
    size_t o = off;
    off += (elems + 255) & ~(size_t)255;
    return o;
  };
  int* base = (int*)d_ws;
  int*      cnt = base + carve(n);
  float*    dis = (float*)(base + carve(n));
  uint16_t* cs  = (uint16_t*)(base + carve((size_t)n * 32));       // n*64 u16
  _Float16* ya  = (_Float16*)(base + carve((size_t)n * 32));       // n*64 f16
  _Float16* ysa = (_Float16*)(base + carve((size_t)(n + 1) * 32)); // (n+1)*64 f16
  _Float16* yb  = (_Float16*)(base + carve((size_t)n * 32));
  _Float16* ysb = (_Float16*)(base + carve((size_t)(n + 1) * 32));
  _Float16* wh  = (_Float16*)(base + carve(10240));                // 20480 f16
  (void)ws_size;

  MegaParams p;
  p.x   = (const float*)d_in[0];
  p.row = (const int*)d_in[1];
  p.col = (const int*)d_in[1] + e;
  p.W0  = (const float*)d_in[2]; p.b0 = (const float*)d_in[3];
  p.W1  = (const float*)d_in[4]; p.b1 = (const float*)d_in[5];
  p.W2  = (const float*)d_in[6]; p.b2 = (const float*)d_in[7];
  p.out = (float*)d_out;
  p.cnt = cnt; p.dis = dis; p.cs = cs;
  p.ya = ya; p.ysa = ysa; p.yb = yb; p.ysb = ysb; p.wh = wh;

  // dropout keys: fold_in(jax.random.key(1), i) = threefry2x32([0,1],[0,i])
  for (uint32_t i = 0; i < 3; ++i) tf2x32(0u, 1u, 0u, i, &p.dk[2*i], &p.dk[2*i+1]);

  p.n = n; p.e = e;
  p.rpx     = (n + 7) / 8;           // rows per XCD slice
  p.nchunk8 = ((e + 255) / 256) * 8; // 25000 virtual fill blocks
  p.nbdrop  = (n * 64) / 256;        // 12500 (exact)
  p.nbconv  = (n + 15) / 16;         // 3125

  // co-resident grid: blocks/CU from the occupancy query (deterministic)
  int occ = 0;
  if (hipOccupancyMaxActiveBlocksPerMultiprocessor(&occ, k_mega, 256, 0)
          != hipSuccess || occ < 1) occ = 4;
  if (occ > 8) occ = 8;
  const int nb = occ * 256;          // multiple of 8 (owner math needs this)

  void* args[] = { (void*)&p };
  hipLaunchCooperativeKernel((const void*)k_mega, dim3(nb), dim3(256),
                             args, 0u, stream);
}

// Round 11
// 222.763 us; speedup vs baseline: 3.8723x; 3.8723x over previous
//
#include <hip/hip_runtime.h>
#include <stdint.h>

typedef _Float16 half8 __attribute__((ext_vector_type(8)));
typedef float float4v __attribute__((ext_vector_type(4)));

__host__ __device__ inline void tf2x32(uint32_t k0, uint32_t k1,
                                       uint32_t x0, uint32_t x1,
                                       uint32_t* o0, uint32_t* o1) {
  const uint32_t ks2 = k0 ^ k1 ^ 0x1BD11BDAu;
#define ROTL(v, s) (((v) << (s)) | ((v) >> (32 - (s))))
#define RND(r) do { x0 += x1; x1 = ROTL(x1, r); x1 ^= x0; } while (0)
  x0 += k0; x1 += k1;
  RND(13); RND(15); RND(26); RND(6);
  x0 += k1; x1 += ks2 + 1u;
  RND(17); RND(29); RND(16); RND(24);
  x0 += ks2; x1 += k0 + 2u;
  RND(13); RND(15); RND(26); RND(6);
  x0 += k0; x1 += k1 + 3u;
  RND(17); RND(29); RND(16); RND(24);
  x0 += k1; x1 += ks2 + 4u;
  RND(13); RND(15); RND(26); RND(6);
  x0 += ks2; x1 += k0 + 5u;
  *o0 = x0; *o1 = x1;
#undef RND
#undef ROTL
}

__device__ inline bool drop_keep(uint32_t k0, uint32_t k1, uint32_t idx) {
  uint32_t o0, o1;
  tf2x32(k0, k1, 0u, idx, &o0, &o1);
  uint32_t bits = o0 ^ o1;
  float u = __uint_as_float((bits >> 9) | 0x3f800000u) - 1.0f;
  return u < 0.4f;
}

// XCD-owned slotted-CSR fill. Grid = 8 * nchunks. Block b: chunk = b>>3,
// owner slice = b&7 (round-robins over XCDs). Only edges whose row falls in
// the owner's contiguous range are handled -> every cs line + cnt atomic is
// single-XCD (1 writeback copy). Edge re-read 8x is L3-absorbed.
__global__ void k_fill2(const int* __restrict__ row, const int* __restrict__ col,
                        int* __restrict__ cnt, uint16_t* __restrict__ cs,
                        int e, int rows_per_xcd) {
  const int owner = blockIdx.x & 7;
  const int i = (blockIdx.x >> 3) * 256 + threadIdx.x;
  if (i < e) {
    int r = row[i];
    if (r / rows_per_xcd == owner) {
      int pos = atomicAdd(&cnt[r], 1);
      if (pos < 64) cs[(r << 6) + pos] = (uint16_t)col[i];
    }
  }
}

// After fill: layer-0 dropout (fp32 -> f16 y and dis-scaled ys), dis[r],
// pad each row's cs slots to a multiple of 8 with dummy index n (zero row),
// zero the dummy rows, and (first blocks) convert W0/W1/W2 to f16 W^T.
__global__ void k_drop(const float* __restrict__ x, const int* __restrict__ cnt,
                       uint16_t* __restrict__ cs, float* __restrict__ dis,
                       _Float16* __restrict__ y, _Float16* __restrict__ ys,
                       _Float16* __restrict__ ysb, uint32_t k0, uint32_t k1,
                       int n, int nd,
                       const float* __restrict__ W0, const float* __restrict__ W1,
                       const float* __restrict__ W2, _Float16* __restrict__ wh) {
  int i = blockIdx.x * 256 + threadIdx.x;
  if (i < 20480) {
    int d = i;
    if (d < 8192) {
      int o = d >> 7, k = d & 127;
      wh[d] = (_Float16)W0[k * 64 + o];
    } else if (d < 16384) {
      int d1 = d - 8192, o = d1 >> 7, k = d1 & 127;
      wh[d] = (_Float16)W1[k * 64 + o];
    } else {
      int d2 = d - 16384, o = d2 >> 7, k = d2 & 127;
      wh[d] = (_Float16)W2[k * 32 + o];
    }
  }
  if (i < 64) {                        // zero dummy gather rows (index n)
    ys[((size_t)n << 6) + i]  = (_Float16)0.f;
    ysb[((size_t)n << 6) + i] = (_Float16)0.f;
  }
  if (i < nd) {
    const int r = i >> 6;
    const int t = i & 63;
    const int d = cnt[r];
    const float dis_r = (d > 0) ? rsqrtf((float)d) : 0.0f;
    float v = drop_keep(k0, k1, (uint32_t)i) ? x[i] * 2.5f : 0.0f;
    y[i]  = (_Float16)v;
    ys[i] = (_Float16)(dis_r * v);
    if (t == 0) dis[r] = dis_r;
    const int cn = d < 64 ? d : 64;
    const int rnd = (cn + 7) & ~7;
    if (t >= cn && t < rnd) cs[(r << 6) + t] = (uint16_t)n;  // pad slot
  }
}

// Fused conv. Block = 256 threads = 4 waves, R = 16 rows. Activations f16.
// Phase 1: per-wave gather p_r = -dis_r * sum_e ys[c_e] over padded slots
//          (8-deep batches, NO masking: pad slots hit the zeroed dummy row).
//          Depth 8 is deliberate: depth 16 made the allocator serialize the
//          loads (VGPR 20, R9/R10 post-mortem). This shape compiles to ~36
//          VGPR with all 8 gathers in flight.
// Phase 2: MFMA 16x16x32_f16; A = [y_r | p_r] tile from LDS, B = global W^T.
// Phase 3: epilogue: +bias, relu, next-layer dropout; dual store y / ys.
template<int COUT, bool RELU, bool DROPN, bool WBF>
__global__ __launch_bounds__(256, 8) void k_conv(
    const _Float16* __restrict__ yg, const _Float16* __restrict__ ysg,
    const int* __restrict__ cnt, const uint16_t* __restrict__ cs,
    const float* __restrict__ dis, const _Float16* __restrict__ wt,
    const float* __restrict__ b, float* __restrict__ outf,
    _Float16* __restrict__ outb, _Float16* __restrict__ outs,
    uint32_t nk0, uint32_t nk1, int n) {
  constexpr int R  = 16;
  constexpr int TS = 136;
  __shared__ __align__(16) _Float16 xp[R][TS];

  const int wave = threadIdx.x >> 6;
  const int t    = threadIdx.x & 63;
  const int row0 = blockIdx.x * R;

  // ---- Phase 1: gather ----
  for (int i = 0; i < 4; ++i) {
    const int rl = wave * 4 + i;
    const int r  = row0 + rl;
    if (r < n) {
      float acc = 0.0f;
      const int d   = cnt[r];
      const int cn  = d < 64 ? d : 64;
      const int rnd = (cn + 7) & ~7;            // padded slot count
      const int base = r << 6;
      for (int j = 0; j < rnd; j += 8) {        // 8-deep batches, no masking
        const uint4 cc = *(const uint4*)&cs[base + j];
        uint32_t c[8];
        c[0] = cc.x & 0xffffu; c[1] = cc.x >> 16;
        c[2] = cc.y & 0xffffu; c[3] = cc.y >> 16;
        c[4] = cc.z & 0xffffu; c[5] = cc.z >> 16;
        c[6] = cc.w & 0xffffu; c[7] = cc.w >> 16;
        _Float16 xv[8];
        #pragma unroll
        for (int k = 0; k < 8; ++k) xv[k] = ysg[(c[k] << 6) + t];
        #pragma unroll
        for (int k = 0; k < 8; ++k) acc += (float)xv[k];
      }
      xp[rl][t]      = yg[(uint32_t)(r << 6) + t];
      xp[rl][64 + t] = (_Float16)(-dis[r] * acc);
    }
  }
  __syncthreads();

  // ---- Phase 2: MFMA (B fragments from global W^T) ----
  constexpr int NW = COUT / 16;
  const int nn   = t & 15;
  const int quad = t >> 4;
  if (wave < NW) {
    const int colg = wave * 16 + nn;
    float4v acc = {0.f, 0.f, 0.f, 0.f};
    #pragma unroll
    for (int ks = 0; ks < 4; ++ks) {
      half8 a  = *(const half8*)&xp[nn][quad * 8 + 32 * ks];
      half8 bb = *(const half8*)&wt[(size_t)colg * 128 + quad * 8 + 32 * ks];
      acc = __builtin_amdgcn_mfma_f32_16x16x32_f16(a, bb, acc, 0, 0, 0);
    }
    // ---- Phase 3: epilogue ----
    const float bias = b[colg];
    #pragma unroll
    for (int rg = 0; rg < 4; ++rg) {
      const int rl = quad * 4 + rg;
      const int rr = row0 + rl;
      if (rr < n) {
        float v = acc[rg] + bias;
        if (RELU) v = fmaxf(v, 0.0f);
        if (DROPN) {
          if (drop_keep(nk0, nk1, (uint32_t)(rr * 64 + colg))) v *= 2.5f;
          else v = 0.0f;
        }
        if (WBF) {
          outb[(size_t)rr * COUT + colg] = (_Float16)v;
          outs[(size_t)rr * COUT + colg] = (_Float16)(dis[rr] * v);
        } else {
          outf[(size_t)rr * COUT + colg] = v;
        }
      }
    }
  }
}

extern "C" void kernel_launch(void* const* d_in, const int* in_sizes, int n_in,
                              void* d_out, int out_size, void* d_ws, size_t ws_size,
                              hipStream_t stream) {
  const float* x   = (const float*)d_in[0];
  const int*   ei  = (const int*)d_in[1];
  const float* W0  = (const float*)d_in[2];
  const float* b0  = (const float*)d_in[3];
  const float* W1f = (const float*)d_in[4];
  const float* b1  = (const float*)d_in[5];
  const float* W2  = (const float*)d_in[6];
  const float* b2  = (const float*)d_in[7];
  float* out = (float*)d_out;

  const int n = in_sizes[0] / 64;   // 50000
  const int e = in_sizes[1] / 2;    // 800000
  const int* row = ei;
  const int* col = ei + e;

  size_t off = 0;
  auto carve = [&](size_t elems) {   // elems in int32 units, 1KB-aligned
    size_t o = off;
    off += (elems + 255) & ~(size_t)255;
    return o;
  };
  int* base = (int*)d_ws;
  int*      cnt = base + carve(n);
  float*    dis = (float*)(base + carve(n));
  uint16_t* cs  = (uint16_t*)(base + carve((size_t)n * 32));       // n*64 u16
  _Float16* ya  = (_Float16*)(base + carve((size_t)n * 32));       // n*64 f16
  _Float16* ysa = (_Float16*)(base + carve((size_t)(n + 1) * 32)); // (n+1)*64 f16
  _Float16* yb  = (_Float16*)(base + carve((size_t)n * 32));
  _Float16* ysb = (_Float16*)(base + carve((size_t)(n + 1) * 32));
  _Float16* wh  = (_Float16*)(base + carve(10240));                // 20480 f16
  (void)ws_size;
  _Float16* wh0 = wh;            // [64][128]
  _Float16* wh1 = wh + 8192;     // [64][128]
  _Float16* wh2 = wh + 16384;    // [32][128]

  // dropout keys: fold_in(jax.random.key(1), i) = threefry2x32([0,1],[0,i])
  uint32_t dk[3][2];
  for (uint32_t i = 0; i < 3; ++i) tf2x32(0u, 1u, 0u, i, &dk[i][0], &dk[i][1]);

  hipMemsetAsync(cnt, 0, (size_t)n * 4, stream);

  const int nchunk = (e + 255) / 256;    // 3125
  const int bd = ((n * 64) + 255) / 256; // 12500
  const int bc = (n + 15) / 16;          // 3125
  const int rpx = (n + 7) / 8;           // rows per XCD slice (6250)

  k_fill2<<<nchunk * 8, 256, 0, stream>>>(row, col, cnt, cs, e, rpx);
  k_drop<<<bd, 256, 0, stream>>>(x, cnt, cs, dis, ya, ysa, ysb,
                                 dk[0][0], dk[0][1], n, n * 64,
                                 W0, W1f, W2, wh);

  k_conv<64, true,  true,  true ><<<bc, 256, 0, stream>>>(
      ya, ysa, cnt, cs, dis, wh0, b0, nullptr, yb, ysb, dk[1][0], dk[1][1], n);
  k_conv<64, true,  true,  true ><<<bc, 256, 0, stream>>>(
      yb, ysb, cnt, cs, dis, wh1, b1, nullptr, ya, ysa, dk[2][0], dk[2][1], n);
  k_conv<32, false, false, false><<<bc, 256, 0, stream>>>(
      ya, ysa, cnt, cs, dis, wh2, b2, out, nullptr, nullptr, 0u, 0u, n);
}